// Round 3
// baseline (211.107 us; speedup 1.0000x reference)
//
#include <hip/hip_runtime.h>

#define SDIM 14
#define L_COORD 5.0f
#define L_NOOBJ 0.5f
#define NIMG 4096
#define CELLS (NIMG * SDIM * SDIM)      // 802816
#define BLOCK 256
#define CPB BLOCK                        // 256 cells per tile
#define NTILE (CELLS / CPB)              // 3136 tiles
#define TPB 2                            // tiles per block, software-pipelined
#define GRID (NTILE / TPB)               // 1568 blocks
#define CELL_F 30
#define TILE_F (CPB * CELL_F)            // 7680 floats per tensor per tile

// LDS: only box channels (0..9) of both tensors, transposed per cell.
// stride 10 keeps float2 writes/reads 8-B aligned (cell*10 + even c is even).
// 4-way bank conflict on per-cell reads is 1.58x on a non-critical path.
#define PBOX 0
#define TBOX (CPB * 10)
#define LDSF (2 * CPB * 10)              // 5120 floats = 20 KiB

__global__ __launch_bounds__(BLOCK, 3) void yolo_partial(
    const float* __restrict__ pred, const float* __restrict__ targ,
    float* __restrict__ partial) {
    __shared__ float lds[LDSF];
    __shared__ float wsum[BLOCK / 64];
    const int tid = threadIdx.x;
    const int tile0 = blockIdx.x * TPB;

    float acc = 0.0f;
    float2 p[15], t[15];

    // ---- prologue: load tile 0 (coalesced float2; pair never straddles a cell) ----
    {
        const float* P = pred + (size_t)tile0 * TILE_F;
        const float* T = targ + (size_t)tile0 * TILE_F;
#pragma unroll
        for (int j = 0; j < 15; ++j) {
            const int idx = tid + j * BLOCK;           // 0..3839
            p[j] = *reinterpret_cast<const float2*>(P + 2 * idx);
            t[j] = *reinterpret_cast<const float2*>(T + 2 * idx);
        }
    }

#pragma unroll
    for (int b = 0; b < TPB; ++b) {
        // ---- scatter box channels to LDS; class diffs stay in registers ----
        // pc = (tid + j*256) % 15 cycles all 15 values per thread:
        // exactly 5 box pairs + 10 class pairs each.
        float2 dif[15];                                // statically indexed by j
#pragma unroll
        for (int j = 0; j < 15; ++j) {
            const int idx = tid + j * BLOCK;
            const int cell = idx / 15;
            const int pc = idx % 15;
            if (pc < 5) {
                *reinterpret_cast<float2*>(&lds[PBOX + cell * 10 + 2 * pc]) = p[j];
                *reinterpret_cast<float2*>(&lds[TBOX + cell * 10 + 2 * pc]) = t[j];
            } else {
                dif[j].x = p[j].x - t[j].x;
                dif[j].y = p[j].y - t[j].y;
            }
        }

        // ---- issue NEXT tile's global loads now; they stay in flight across
        //      the raw barrier (no vmcnt drain) and hide under the compute ----
        if (b + 1 < TPB) {
            const float* P = pred + (size_t)(tile0 + b + 1) * TILE_F;
            const float* T = targ + (size_t)(tile0 + b + 1) * TILE_F;
#pragma unroll
            for (int j = 0; j < 15; ++j) {
                const int idx = tid + j * BLOCK;
                p[j] = *reinterpret_cast<const float2*>(P + 2 * idx);
                t[j] = *reinterpret_cast<const float2*>(T + 2 * idx);
            }
        }

        // raw barrier: drain only LDS writes (lgkm), NOT the global prefetch (vm).
        asm volatile("s_waitcnt lgkmcnt(0)" ::: "memory");
        __builtin_amdgcn_s_barrier();

        // ---- per-cell loss (cell = tid) from LDS box data ----
        float Pb[10], Tb[10];
#pragma unroll
        for (int c = 0; c < 10; c += 2) {
            const float2 a = *reinterpret_cast<const float2*>(&lds[PBOX + tid * 10 + c]);
            const float2 bb = *reinterpret_cast<const float2*>(&lds[TBOX + tid * 10 + c]);
            Pb[c] = a.x; Pb[c + 1] = a.y;
            Tb[c] = bb.x; Tb[c + 1] = bb.y;
        }

        const float d4 = Pb[4] - Tb[4];
        const float d9 = Pb[9] - Tb[9];
        const float noobj_l = L_NOOBJ * (d4 * d4 + d9 * d9);

        const float invS = 1.0f / (float)SDIM;
        const float t1x = Tb[0] * invS - Tb[2] * 0.5f;
        const float t1y = Tb[1] * invS - Tb[3] * 0.5f;
        const float t2x = Tb[0] * invS + Tb[2] * 0.5f;
        const float t2y = Tb[1] * invS + Tb[3] * 0.5f;
        const float area_t = (t2x - t1x) * (t2y - t1y);

        float iou0 = 0.0f, iou1 = 0.0f;
#pragma unroll
        for (int k = 0; k < 2; ++k) {
            const float bx = Pb[5 * k + 0], by = Pb[5 * k + 1];
            const float bw = Pb[5 * k + 2], bh = Pb[5 * k + 3];
            const float p1x = bx * invS - bw * 0.5f;
            const float p1y = by * invS - bh * 0.5f;
            const float p2x = bx * invS + bw * 0.5f;
            const float p2y = by * invS + bh * 0.5f;
            const float ltx = fmaxf(p1x, t1x), lty = fmaxf(p1y, t1y);
            const float rbx = fminf(p2x, t2x), rby = fminf(p2y, t2y);
            const float wx = fmaxf(rbx - ltx, 0.0f);
            const float wy = fmaxf(rby - lty, 0.0f);
            const float inter = wx * wy;
            const float area_p = (p2x - p1x) * (p2y - p1y);
            const float v = inter / (area_p + area_t - inter);
            if (k == 0) iou0 = v; else iou1 = v;
        }

        const bool pick1 = (iou0 <= iou1);
        const float iou_best = pick1 ? iou1 : iou0;
        const float psx = pick1 ? Pb[5] : Pb[0];
        const float psy = pick1 ? Pb[6] : Pb[1];
        const float psw = pick1 ? Pb[7] : Pb[2];
        const float psh = pick1 ? Pb[8] : Pb[3];
        const float psc = pick1 ? Pb[9] : Pb[4];
        const float tsx = pick1 ? Tb[5] : Tb[0];
        const float tsy = pick1 ? Tb[6] : Tb[1];
        const float tsw = pick1 ? Tb[7] : Tb[2];
        const float tsh = pick1 ? Tb[8] : Tb[3];

        const float dx = psx - tsx, dy = psy - tsy;
        const float dw = sqrtf(psw) - sqrtf(tsw);   // inputs in [0.01,1]: safe
        const float dh = sqrtf(psh) - sqrtf(tsh);
        const float reg = dx * dx + dy * dy + dw * dw + dh * dh;
        const float dconf = psc - iou_best;
        const float obj_l = L_COORD * reg + dconf * dconf;  // class handled below

        acc += (Tb[4] > 0.0f) ? obj_l : noobj_l;

        // ---- class accumulation: owner cell's obj gate read from scattered T ----
        // obj is exactly 0.0 or 1.0 (setup), so obj*x == gated x bit-exactly.
#pragma unroll
        for (int j = 0; j < 15; ++j) {
            const int idx = tid + j * BLOCK;
            const int cell = idx / 15;
            const int pc = idx % 15;
            if (pc >= 5) {
                const float obj = lds[TBOX + cell * 10 + 4];
                acc += obj * (dif[j].x * dif[j].x);
                acc += obj * (dif[j].y * dif[j].y);
            }
        }

        // barrier before next iteration's scatter overwrites LDS
        asm volatile("s_waitcnt lgkmcnt(0)" ::: "memory");
        __builtin_amdgcn_s_barrier();
    }

    // ---- block reduction (once per block, not per tile) ----
#pragma unroll
    for (int off = 32; off > 0; off >>= 1)
        acc += __shfl_down(acc, off, 64);
    const int lane = tid & 63;
    const int wave = tid >> 6;
    if (lane == 0) wsum[wave] = acc;
    __syncthreads();
    if (tid == 0)
        partial[blockIdx.x] = wsum[0] + wsum[1] + wsum[2] + wsum[3];
}

__global__ __launch_bounds__(256) void yolo_final(
    const float* __restrict__ partial, float* __restrict__ out) {
    float s = 0.0f;
    for (int i = threadIdx.x; i < GRID; i += 256) s += partial[i];
#pragma unroll
    for (int off = 32; off > 0; off >>= 1)
        s += __shfl_down(s, off, 64);
    __shared__ float wsum[256 / 64];
    const int lane = threadIdx.x & 63;
    const int wave = threadIdx.x >> 6;
    if (lane == 0) wsum[wave] = s;
    __syncthreads();
    if (threadIdx.x == 0)
        out[0] = (wsum[0] + wsum[1] + wsum[2] + wsum[3]) * (1.0f / (float)NIMG);
}

extern "C" void kernel_launch(void* const* d_in, const int* in_sizes, int n_in,
                              void* d_out, int out_size, void* d_ws, size_t ws_size,
                              hipStream_t stream) {
    const float* pred = (const float*)d_in[0];
    const float* targ = (const float*)d_in[1];
    float* out = (float*)d_out;
    float* partial = (float*)d_ws;   // GRID floats = 6.1 KB scratch

    yolo_partial<<<GRID, BLOCK, 0, stream>>>(pred, targ, partial);
    yolo_final<<<1, 256, 0, stream>>>(partial, out);
}

// Round 4
// 194.090 us; speedup vs baseline: 1.0877x; 1.0877x over previous
//
#include <hip/hip_runtime.h>

#define SDIM 14
#define L_COORD 5.0f
#define L_NOOBJ 0.5f
#define BATCH 4096
#define CELLS (BATCH * SDIM * SDIM)   // 802816
#define BLOCK 128
#define NBLOCKS (CELLS / BLOCK)       // 6272
#define CELL_F 30
#define BLK_F (BLOCK * CELL_F)        // 3840 floats per tensor per block

// Identical to round-2 kernel EXCEPT phase-1 global loads are non-temporal
// (nt flag): single A/B variable. Theory: the ~2.6 TB/s plateau across four
// structurally different kernels is the L3-hit data path saturating (192.7 MB
// footprint is L3-resident; FETCH_SIZE shows exactly half the bytes from HBM).
// nt streams the data on the pure-HBM path measured at 6.3 TB/s (m13).
typedef float f2v __attribute__((ext_vector_type(2)));

#define PBOX 0                        // [128][10]  box stride 10
#define TBOX (BLOCK * 10)             // [128][10]
#define DCLS (2 * BLOCK * 10)         // [128][22]  class-diff, stride 22
#define WSUM (DCLS + BLOCK * 22)      // [2]
#define LDS_FLOATS (WSUM + 2)         // 5378 floats = 21512 B -> 7 blocks/CU

__global__ __launch_bounds__(BLOCK, 4) void yolo_partial(
    const float* __restrict__ pred, const float* __restrict__ targ,
    float* __restrict__ partial) {
    __shared__ float lds[LDS_FLOATS];

    const int tid = threadIdx.x;
    const size_t base = (size_t)blockIdx.x * BLK_F;
    const float* P = pred + base;
    const float* T = targ + base;

    // ---- phase 1: coalesced NON-TEMPORAL loads (float2, never straddles
    //      a cell: channels (idx%15)*2, +1 both < 30) ----
    f2v p2[15], t2[15];
#pragma unroll
    for (int j = 0; j < 15; ++j) {
        const int idx = tid + j * BLOCK;          // 0..1919
        p2[j] = __builtin_nontemporal_load(reinterpret_cast<const f2v*>(P + 2 * idx));
        t2[j] = __builtin_nontemporal_load(reinterpret_cast<const f2v*>(T + 2 * idx));
    }

    // ---- phase 2: scatter box to LDS transpose; class -> diff store ----
#pragma unroll
    for (int j = 0; j < 15; ++j) {
        const int idx = tid + j * BLOCK;
        const int cell = idx / 15;
        const int c = (idx % 15) * 2;             // even channel 0..28
        if (c < 10) {
            lds[PBOX + cell * 10 + c]     = p2[j].x;
            lds[PBOX + cell * 10 + c + 1] = p2[j].y;
            lds[TBOX + cell * 10 + c]     = t2[j].x;
            lds[TBOX + cell * 10 + c + 1] = t2[j].y;
        } else {
            lds[DCLS + cell * 22 + (c - 10)]     = p2[j].x - t2[j].x;
            lds[DCLS + cell * 22 + (c - 10) + 1] = p2[j].y - t2[j].y;
        }
    }
    __syncthreads();

    // ---- phase 3: per-cell compute from compact LDS ----
    float Pb[10], Tb[10];
#pragma unroll
    for (int j = 0; j < 5; ++j) {
        const float2 a = *reinterpret_cast<const float2*>(&lds[PBOX + tid * 10 + 2 * j]);
        const float2 b = *reinterpret_cast<const float2*>(&lds[TBOX + tid * 10 + 2 * j]);
        Pb[2 * j] = a.x; Pb[2 * j + 1] = a.y;
        Tb[2 * j] = b.x; Tb[2 * j + 1] = b.y;
    }

    // class loss: same channel order and expression shape as round 2
    float cls = 0.0f;
#pragma unroll
    for (int j = 0; j < 10; ++j) {
        const float2 d = *reinterpret_cast<const float2*>(&lds[DCLS + tid * 22 + 2 * j]);
        cls += d.x * d.x;
        cls += d.y * d.y;
    }

    // ---- branchless per-cell loss (identical arithmetic to prior rounds) ----
    const float d4 = Pb[4] - Tb[4];
    const float d9 = Pb[9] - Tb[9];
    const float noobj_l = L_NOOBJ * (d4 * d4 + d9 * d9);

    const float invS = 1.0f / (float)SDIM;
    const float t1x = Tb[0] * invS - Tb[2] * 0.5f;
    const float t1y = Tb[1] * invS - Tb[3] * 0.5f;
    const float t2x = Tb[0] * invS + Tb[2] * 0.5f;
    const float t2y = Tb[1] * invS + Tb[3] * 0.5f;
    const float area_t = (t2x - t1x) * (t2y - t1y);

    float iou0 = 0.0f, iou1 = 0.0f;
#pragma unroll
    for (int k = 0; k < 2; ++k) {
        const float bx = Pb[5 * k + 0], by = Pb[5 * k + 1];
        const float bw = Pb[5 * k + 2], bh = Pb[5 * k + 3];
        const float p1x = bx * invS - bw * 0.5f;
        const float p1y = by * invS - bh * 0.5f;
        const float p2x = bx * invS + bw * 0.5f;
        const float p2y = by * invS + bh * 0.5f;
        const float ltx = fmaxf(p1x, t1x), lty = fmaxf(p1y, t1y);
        const float rbx = fminf(p2x, t2x), rby = fminf(p2y, t2y);
        const float wx = fmaxf(rbx - ltx, 0.0f);
        const float wy = fmaxf(rby - lty, 0.0f);
        const float inter = wx * wy;
        const float area_p = (p2x - p1x) * (p2y - p1y);
        const float v = inter / (area_p + area_t - inter);
        if (k == 0) iou0 = v; else iou1 = v;
    }

    const bool pick1 = (iou0 <= iou1);
    const float iou_best = pick1 ? iou1 : iou0;
    const float psx = pick1 ? Pb[5] : Pb[0];
    const float psy = pick1 ? Pb[6] : Pb[1];
    const float psw = pick1 ? Pb[7] : Pb[2];
    const float psh = pick1 ? Pb[8] : Pb[3];
    const float psc = pick1 ? Pb[9] : Pb[4];
    const float tsx = pick1 ? Tb[5] : Tb[0];
    const float tsy = pick1 ? Tb[6] : Tb[1];
    const float tsw = pick1 ? Tb[7] : Tb[2];
    const float tsh = pick1 ? Tb[8] : Tb[3];

    const float dx = psx - tsx, dy = psy - tsy;
    const float dw = sqrtf(psw) - sqrtf(tsw);   // inputs in [0.01,1]: safe
    const float dh = sqrtf(psh) - sqrtf(tsh);
    const float reg = dx * dx + dy * dy + dw * dw + dh * dh;
    const float dconf = psc - iou_best;
    const float obj_l = cls + L_COORD * reg + dconf * dconf;

    float loss = (Tb[4] > 0.0f) ? obj_l : noobj_l;

    // ---- wave (64-lane) shuffle reduction ----
#pragma unroll
    for (int off = 32; off > 0; off >>= 1)
        loss += __shfl_down(loss, off, 64);

    const int lane = tid & 63;
    const int wave = tid >> 6;
    if (lane == 0) lds[WSUM + wave] = loss;
    __syncthreads();
    if (tid == 0)
        partial[blockIdx.x] = lds[WSUM + 0] + lds[WSUM + 1];
}

__global__ __launch_bounds__(256) void yolo_final(
    const float* __restrict__ partial, float* __restrict__ out) {
    float s = 0.0f;
    for (int i = threadIdx.x; i < NBLOCKS; i += 256) s += partial[i];
#pragma unroll
    for (int off = 32; off > 0; off >>= 1)
        s += __shfl_down(s, off, 64);
    __shared__ float wsum[256 / 64];
    const int lane = threadIdx.x & 63;
    const int wave = threadIdx.x >> 6;
    if (lane == 0) wsum[wave] = s;
    __syncthreads();
    if (threadIdx.x == 0)
        out[0] = (wsum[0] + wsum[1] + wsum[2] + wsum[3]) * (1.0f / (float)BATCH);
}

extern "C" void kernel_launch(void* const* d_in, const int* in_sizes, int n_in,
                              void* d_out, int out_size, void* d_ws, size_t ws_size,
                              hipStream_t stream) {
    const float* pred = (const float*)d_in[0];
    const float* targ = (const float*)d_in[1];
    float* out = (float*)d_out;
    float* partial = (float*)d_ws;   // NBLOCKS floats = 24.5 KB scratch

    yolo_partial<<<NBLOCKS, BLOCK, 0, stream>>>(pred, targ, partial);
    yolo_final<<<1, 256, 0, stream>>>(partial, out);
}

// Round 5
// 193.444 us; speedup vs baseline: 1.0913x; 1.0033x over previous
//
#include <hip/hip_runtime.h>

#define SDIM 14
#define L_COORD 5.0f
#define L_NOOBJ 0.5f
#define BATCH 4096
#define CELLS (BATCH * SDIM * SDIM)   // 802816
#define BLOCK 256
#define NBLOCKS (CELLS / BLOCK)       // 3136
#define CELL_F 30
#define BLK_F (BLOCK * CELL_F)        // 7680 floats per tensor per block
#define BLK_F4 (BLK_F / 4)            // 1920 float4 per tensor per block

typedef float f4v __attribute__((ext_vector_type(4)));

// Round-0 structure (float4 -> 60 KB linear LDS -> per-cell compute) with ONE
// change vs round 4: staging loads are dwordx4 NON-TEMPORAL (16 B/lane on the
// streaming/HBM path). Round 4 proved nt is worth +30% (L3-hit path was the
// 2.6 TB/s cap); this round tests whether 8B->16B lanes closes the remaining
// gap to the ~6.3 TB/s streaming ceiling (m13 float4 copy / 6.75 TB/s fills).
__global__ __launch_bounds__(BLOCK) void yolo_partial(
    const float* __restrict__ pred, const float* __restrict__ targ,
    float* __restrict__ partial) {
    // 60 KB LDS: [0, BLK_F) = pred cells, [BLK_F, 2*BLK_F) = targ cells
    __shared__ float s[2 * BLK_F];

    // ---- staging: 15 x nt-float4 per thread, all in flight before ds_write ----
    const size_t base = (size_t)blockIdx.x * BLK_F;
    const f4v* pP = reinterpret_cast<const f4v*>(pred + base);
    const f4v* pT = reinterpret_cast<const f4v*>(targ + base);
    f4v v[15];
#pragma unroll
    for (int j = 0; j < 15; ++j) {
        const int idx = threadIdx.x + j * BLOCK;  // 0..3839
        const f4v* src = (idx < BLK_F4) ? (pP + idx) : (pT + (idx - BLK_F4));
        v[j] = __builtin_nontemporal_load(src);
    }
    f4v* s4 = reinterpret_cast<f4v*>(s);
#pragma unroll
    for (int j = 0; j < 15; ++j)
        s4[threadIdx.x + j * BLOCK] = v[j];
    __syncthreads();

    // ---- per-cell compute from LDS (verbatim round 0: absmax was 0) ----
    const float* Pc = s + threadIdx.x * CELL_F;
    const float* Tc = s + BLK_F + threadIdx.x * CELL_F;

    float loss;
    if (Tc[4] > 0.0f) {
        // class loss (channels 10..29)
        float cls = 0.0f;
#pragma unroll
        for (int c = 10; c < 30; ++c) { float d = Pc[c] - Tc[c]; cls += d * d; }

        const float invS = 1.0f / (float)SDIM;
        const float t1x = Tc[0] * invS - Tc[2] * 0.5f;
        const float t1y = Tc[1] * invS - Tc[3] * 0.5f;
        const float t2x = Tc[0] * invS + Tc[2] * 0.5f;
        const float t2y = Tc[1] * invS + Tc[3] * 0.5f;
        const float area_t = (t2x - t1x) * (t2y - t1y);

        float iou0 = 0.0f, iou1 = 0.0f;
#pragma unroll
        for (int k = 0; k < 2; ++k) {
            const float bx = Pc[5 * k + 0], by = Pc[5 * k + 1];
            const float bw = Pc[5 * k + 2], bh = Pc[5 * k + 3];
            const float p1x = bx * invS - bw * 0.5f;
            const float p1y = by * invS - bh * 0.5f;
            const float p2x = bx * invS + bw * 0.5f;
            const float p2y = by * invS + bh * 0.5f;
            const float ltx = fmaxf(p1x, t1x), lty = fmaxf(p1y, t1y);
            const float rbx = fminf(p2x, t2x), rby = fminf(p2y, t2y);
            const float wx = fmaxf(rbx - ltx, 0.0f);
            const float wy = fmaxf(rby - lty, 0.0f);
            const float inter = wx * wy;
            const float area_p = (p2x - p1x) * (p2y - p1y);
            const float v2 = inter / (area_p + area_t - inter);
            if (k == 0) iou0 = v2; else iou1 = v2;
        }

        const bool pick1 = (iou0 <= iou1);
        const float iou_best = pick1 ? iou1 : iou0;
        const float psx = pick1 ? Pc[5] : Pc[0];
        const float psy = pick1 ? Pc[6] : Pc[1];
        const float psw = pick1 ? Pc[7] : Pc[2];
        const float psh = pick1 ? Pc[8] : Pc[3];
        const float psc = pick1 ? Pc[9] : Pc[4];
        const float tsx = pick1 ? Tc[5] : Tc[0];
        const float tsy = pick1 ? Tc[6] : Tc[1];
        const float tsw = pick1 ? Tc[7] : Tc[2];
        const float tsh = pick1 ? Tc[8] : Tc[3];

        const float dx = psx - tsx, dy = psy - tsy;
        const float dw = sqrtf(psw) - sqrtf(tsw);
        const float dh = sqrtf(psh) - sqrtf(tsh);
        const float reg = dx * dx + dy * dy + dw * dw + dh * dh;
        const float dconf = psc - iou_best;
        loss = cls + L_COORD * reg + dconf * dconf;
    } else {
        const float d4 = Pc[4] - Tc[4];
        const float d9 = Pc[9] - Tc[9];
        loss = L_NOOBJ * (d4 * d4 + d9 * d9);
    }

    // ---- wave (64-lane) shuffle reduction ----
#pragma unroll
    for (int off = 32; off > 0; off >>= 1)
        loss += __shfl_down(loss, off, 64);

    __shared__ float wsum[BLOCK / 64];
    const int lane = threadIdx.x & 63;
    const int wave = threadIdx.x >> 6;
    if (lane == 0) wsum[wave] = loss;
    __syncthreads();
    if (threadIdx.x == 0)
        partial[blockIdx.x] = wsum[0] + wsum[1] + wsum[2] + wsum[3];
}

__global__ __launch_bounds__(BLOCK) void yolo_final(
    const float* __restrict__ partial, float* __restrict__ out) {
    float s = 0.0f;
    for (int i = threadIdx.x; i < NBLOCKS; i += BLOCK) s += partial[i];
#pragma unroll
    for (int off = 32; off > 0; off >>= 1)
        s += __shfl_down(s, off, 64);
    __shared__ float wsum[BLOCK / 64];
    const int lane = threadIdx.x & 63;
    const int wave = threadIdx.x >> 6;
    if (lane == 0) wsum[wave] = s;
    __syncthreads();
    if (threadIdx.x == 0)
        out[0] = (wsum[0] + wsum[1] + wsum[2] + wsum[3]) * (1.0f / (float)BATCH);
}

extern "C" void kernel_launch(void* const* d_in, const int* in_sizes, int n_in,
                              void* d_out, int out_size, void* d_ws, size_t ws_size,
                              hipStream_t stream) {
    const float* pred = (const float*)d_in[0];
    const float* targ = (const float*)d_in[1];
    float* out = (float*)d_out;
    float* partial = (float*)d_ws;   // NBLOCKS floats = 12.5 KB scratch

    yolo_partial<<<NBLOCKS, BLOCK, 0, stream>>>(pred, targ, partial);
    yolo_final<<<1, BLOCK, 0, stream>>>(partial, out);
}